// Round 15
// baseline (3216.600 us; speedup 1.0000x reference)
//
#include <hip/hip_runtime.h>
#include <math.h>

#define BB 32
#define SS 400
#define TT 64
#define VV 32000
#define EE 256
#define HH 512

typedef __attribute__((ext_vector_type(4))) float f32x4;
typedef __attribute__((ext_vector_type(8))) short bf16x8t;
typedef __attribute__((ext_vector_type(8))) unsigned short u16x8;
typedef __attribute__((ext_vector_type(4))) unsigned int u32x4;
typedef unsigned long long u64t;

__device__ __forceinline__ ushort f2bf(float x) {
  uint u = __float_as_uint(x);
  return (ushort)((u + 0x7fffu + ((u >> 16) & 1u)) >> 16);
}
__device__ __forceinline__ float bf2f(ushort x) {
  return __uint_as_float(((uint)x) << 16);
}
__device__ __forceinline__ float fsigmoid(float x) {
  return 1.f / (1.f + __expf(-x));
}
__device__ __forceinline__ float ftanh(float x) {
  return 1.f - 2.f / (__expf(2.f * x) + 1.f);
}
__device__ __forceinline__ void gload_lds16(const ushort* g, ushort* l) {
  __builtin_amdgcn_global_load_lds(
      (const __attribute__((address_space(1))) void*)g,
      (__attribute__((address_space(3))) void*)l, 16, 0, 0);
}
__device__ __forceinline__ void unpack8(uint4 u, float* f) {
  f[0] = __uint_as_float(u.x << 16); f[1] = __uint_as_float(u.x & 0xffff0000u);
  f[2] = __uint_as_float(u.y << 16); f[3] = __uint_as_float(u.y & 0xffff0000u);
  f[4] = __uint_as_float(u.z << 16); f[5] = __uint_as_float(u.z & 0xffff0000u);
  f[6] = __uint_as_float(u.w << 16); f[7] = __uint_as_float(u.w & 0xffff0000u);
}

// ---------------------------------------------------------------------------
// init: write initial-h packets (tag 0, slot 0) for both encoder directions
// ---------------------------------------------------------------------------
__global__ __launch_bounds__(256) void init_all_kernel(
    const float* __restrict__ einh, uint* __restrict__ hge,
    uint* __restrict__ hgb)
{
  int i = blockIdx.x * 256 + threadIdx.x;
  if (i < 4096) {
    int c = (i & 127) * 4;
    uint lo = (uint)f2bf(einh[c]) | ((uint)f2bf(einh[c + 1]) << 16);
    uint hi = (uint)f2bf(einh[c + 2]) | ((uint)f2bf(einh[c + 3]) << 16);
    u32x4 pkt = {lo, hi, 0u, 0u};
    *(u32x4*)(hge + (size_t)i * 4) = pkt;
  } else if (i < 8192) {
    int p = i - 4096;
    int c = HH + (p & 127) * 4;
    uint lo = (uint)f2bf(einh[c]) | ((uint)f2bf(einh[c + 1]) << 16);
    uint hi = (uint)f2bf(einh[c + 2]) | ((uint)f2bf(einh[c + 3]) << 16);
    u32x4 pkt = {lo, hi, 0u, 0u};
    *(u32x4*)(hgb + (size_t)p * 4) = pkt;
  }
}

__global__ __launch_bounds__(256) void f2bf_kernel(
    const float* __restrict__ in, ushort* __restrict__ out, long n)
{
  long step = (long)gridDim.x * 256 * 4;
  for (long i = ((long)blockIdx.x * 256 + threadIdx.x) * 4; i < n; i += step) {
    float4 v = *(const float4*)(in + i);
    ushort4 o;
    o.x = f2bf(v.x); o.y = f2bf(v.y); o.z = f2bf(v.z); o.w = f2bf(v.w);
    *(ushort4*)(out + i) = o;
  }
}

// gather emb rows (fp32 src) -> bf16 x rows: row = s*32+b
__global__ __launch_bounds__(64) void gather_x_kernel(
    const float* __restrict__ emb, const int* __restrict__ tok, int L,
    ushort* __restrict__ xout)
{
  int row = blockIdx.x;
  int b = row & 31, s = row >> 5;
  int t = tok[b * L + s];
  float4 v = ((const float4*)(emb + (size_t)t * EE))[threadIdx.x];
  ushort4 o;
  o.x = f2bf(v.x); o.y = f2bf(v.y); o.z = f2bf(v.z); o.w = f2bf(v.w);
  ((ushort4*)(xout + (size_t)row * EE))[threadIdx.x] = o;
}

__global__ __launch_bounds__(256) void bias3_kernel(
    const float* a1, const float* a2, const float* b1, const float* b2,
    const float* c1, const float* c2, float* out)
{
  int i = blockIdx.x * 256 + threadIdx.x;
  if (i < 2048) out[i] = a1[i] + a2[i];
  else if (i < 4096) out[i] = b1[i - 2048] + b2[i - 2048];
  else if (i < 6144) out[i] = c1[i - 4096] + c2[i - 4096];
}

// ---------------------------------------------------------------------------
// one 128x128 bf16 MFMA GEMM tile: C[M,N] = act(A[M,K] @ B[N,K]^T + bias)
// flags: 1=tanh, 2=row remap (t*32+b)->(b*TT+t), 4=bf16 out, 8=xw-layout out
// ---------------------------------------------------------------------------
__device__ void gemm_tile_dev(
    const ushort* __restrict__ A, const ushort* __restrict__ B,
    const float* __restrict__ bias, void* __restrict__ Cout,
    int M, int N, int K, int flags, int m0, int n0,
    ushort* Asub, ushort* Bsub)
{
  int tid = threadIdx.x;
  int w = tid >> 6, l = tid & 63;
  int wm = w >> 1, wn = w & 1;

  int srow = 16 * 2 * w + (l >> 2);
  int scol = (l & 3) * 8;
  const ushort* Ar0 = A + (size_t)(m0 + srow) * K + scol;
  const ushort* Ar1 = Ar0 + (size_t)16 * K;
  const ushort* Br0 = B + (size_t)(n0 + srow) * K + scol;
  const ushort* Br1 = Br0 + (size_t)16 * K;
  ushort* ldsA0 = Asub + (2 * w) * 512;
  ushort* ldsA1 = Asub + (2 * w + 1) * 512;
  ushort* ldsB0 = Bsub + (2 * w) * 512;
  ushort* ldsB1 = Bsub + (2 * w + 1) * 512;

  f32x4 acc[4][4];
  #pragma unroll
  for (int i = 0; i < 4; ++i)
    #pragma unroll
    for (int j = 0; j < 4; ++j)
      acc[i][j] = (f32x4){0.f, 0.f, 0.f, 0.f};

  int lr = l & 15, lkb = (l >> 4) * 8;

  for (int k0 = 0; k0 < K; k0 += 32) {
    gload_lds16(Ar0 + k0, ldsA0);
    gload_lds16(Ar1 + k0, ldsA1);
    gload_lds16(Br0 + k0, ldsB0);
    gload_lds16(Br1 + k0, ldsB1);
    __syncthreads();
    bf16x8t af[4], bfv[4];
    #pragma unroll
    for (int mf = 0; mf < 4; ++mf)
      af[mf] = *(const bf16x8t*)&Asub[(wm * 64 + mf * 16 + lr) * 32 + lkb];
    #pragma unroll
    for (int nf = 0; nf < 4; ++nf)
      bfv[nf] = *(const bf16x8t*)&Bsub[(wn * 64 + nf * 16 + lr) * 32 + lkb];
    #pragma unroll
    for (int mf = 0; mf < 4; ++mf)
      #pragma unroll
      for (int nf = 0; nf < 4; ++nf)
        acc[mf][nf] = __builtin_amdgcn_mfma_f32_16x16x32_bf16(
            af[mf], bfv[nf], acc[mf][nf], 0, 0, 0);
    __syncthreads();
  }

  int lg = l >> 4;
  #pragma unroll
  for (int mf = 0; mf < 4; ++mf) {
    #pragma unroll
    for (int nf = 0; nf < 4; ++nf) {
      int n = n0 + wn * 64 + nf * 16 + lr;
      float bv = bias[n];
      #pragma unroll
      for (int r = 0; r < 4; ++r) {
        int m = m0 + wm * 64 + mf * 16 + lg * 4 + r;
        float v = acc[mf][nf][r] + bv;
        if (flags & 1) v = tanhf(v);
        if (flags & 8) {
          int s = m >> 5, b = m & 31;
          int gate = n >> 9, col = n & 511;
          size_t dst = (((size_t)s * 32 + (col >> 4)) * 32 + b) * 64 +
                       (size_t)(col & 15) * 4 + gate;
          ((ushort*)Cout)[dst] = f2bf(v);
        } else {
          int row = (flags & 2) ? ((m & 31) * TT + (m >> 5)) : m;
          if (flags & 4) ((ushort*)Cout)[(size_t)row * N + n] = f2bf(v);
          else           ((float*)Cout)[(size_t)row * N + n] = v;
        }
      }
    }
  }
}

__global__ __launch_bounds__(256) void gemm_mfma_kernel(
    const ushort* __restrict__ A, const ushort* __restrict__ B,
    const float* __restrict__ bias, void* __restrict__ Cout,
    int M, int N, int K, int flags)
{
  __shared__ ushort Asub[128 * 32], Bsub[128 * 32];
  gemm_tile_dev(A, B, bias, Cout, M, N, K, flags,
                (int)blockIdx.y * 128, (int)blockIdx.x * 128, Asub, Bsub);
}

// ---------------------------------------------------------------------------
// Persistent LSTM with tag-in-data packets (R10/R13-proven protocol).
// Blocks < nactive run the LSTM; blocks >= nactive run aux work:
//   first ag (if ag.A != null): grid-stride 128x128 GEMM tiles,
//   then cv: up to 3 f2bf conversion jobs.
// ---------------------------------------------------------------------------
struct PersistArgs {
  const float* W_hh;
  const ushort* xw;          // [steps][32 cblk][32 b][64] bf16
  uint* hpack;               // [2 slots][32 b][128 cp4] 16B packets
  const float* c_init_elem;  // [32][512] fp32 or null
  const float* c_init_bcast; // [512] fp32 or null
  ushort* out_h;             // [steps][32][OS] bf16
  int out_os, out_ofs;
  int steps, backward;
  float* h_final;            // [32][512] fp32 or null
  float* c_final;
};

struct CvtJobs {
  const float* in0; ushort* out0; long n0;
  const float* in1; ushort* out1; long n1;
  const float* in2; ushort* out2; long n2;
};

struct AuxGemm {
  const ushort* A; const ushort* B; const float* bias; void* C;
  int M, N, K, flags;
};

__global__ __launch_bounds__(256) void lstm_persist_kernel(
    PersistArgs A0, PersistArgs A1, int nblk_dir, int nactive,
    CvtJobs cv, AuxGemm ag)
{
  __shared__ ushort ldsW[64 * 512];
  __shared__ ushort ldsH[32 * 512];
  __shared__ ushort ldsX[32 * 64];

  int bid = (int)blockIdx.x;
  int tid = threadIdx.x;
  if (bid >= nactive) {
    int naux = (int)gridDim.x - nactive;
    int aid = bid - nactive;
    if (ag.A) {
      // -------- aux GEMM tiles (runs in persistent kernel's shadow) --------
      int nb = ag.N / 128;
      int ntiles = nb * (ag.M / 128);
      ushort* Asub = ldsW;
      ushort* Bsub = ldsW + 128 * 32;
      for (int t = aid; t < ntiles; t += naux) {
        gemm_tile_dev(ag.A, ag.B, ag.bias, ag.C, ag.M, ag.N, ag.K, ag.flags,
                      (t / nb) * 128, (t % nb) * 128, Asub, Bsub);
        __syncthreads();
      }
    }
    // -------- converter blocks: up to 3 f2bf jobs --------
    long base = ((long)aid * 256 + tid) * 4;
    long step = (long)naux * 256 * 4;
    for (long i = base; i < cv.n0; i += step) {
      float4 v = *(const float4*)(cv.in0 + i);
      ushort4 o;
      o.x = f2bf(v.x); o.y = f2bf(v.y); o.z = f2bf(v.z); o.w = f2bf(v.w);
      *(ushort4*)(cv.out0 + i) = o;
    }
    for (long i = base; i < cv.n1; i += step) {
      float4 v = *(const float4*)(cv.in1 + i);
      ushort4 o;
      o.x = f2bf(v.x); o.y = f2bf(v.y); o.z = f2bf(v.z); o.w = f2bf(v.w);
      *(ushort4*)(cv.out1 + i) = o;
    }
    for (long i = base; i < cv.n2; i += step) {
      float4 v = *(const float4*)(cv.in2 + i);
      ushort4 o;
      o.x = f2bf(v.x); o.y = f2bf(v.y); o.z = f2bf(v.z); o.w = f2bf(v.w);
      *(ushort4*)(cv.out2 + i) = o;
    }
    return;
  }

  PersistArgs a = (bid < nblk_dir) ? A0 : A1;
  int cblk = bid % nblk_dir;
  int c0 = cblk * 16;
  int w = tid >> 6, l = tid & 63;
  int lr = l & 15, kb = (l >> 4) * 8;
  int g = l & 3;
  int col = c0 + w * 4 + (lr >> 2);
  int n = w * 16 + lr;

  // ---- stage W slice (once), swizzled bf16 ----
  {
    int nn = tid >> 2;                   // 0..63
    int kbase = (tid & 3) * 128;
    int rW = (nn & 3) * HH + c0 + (nn >> 2);
    const float4* src = (const float4*)(a.W_hh + (size_t)rW * HH + kbase);
    #pragma unroll
    for (int j = 0; j < 16; ++j) {
      float4 u = src[2 * j], v = src[2 * j + 1];
      u16x8 o;
      o[0] = f2bf(u.x); o[1] = f2bf(u.y); o[2] = f2bf(u.z); o[3] = f2bf(u.w);
      o[4] = f2bf(v.x); o[5] = f2bf(v.y); o[6] = f2bf(v.z); o[7] = f2bf(v.w);
      int k = kbase + j * 8;
      int byte = (nn * 1024 + k * 2) ^ ((nn & 7) << 4);
      *(u16x8*)((char*)ldsW + byte) = o;
    }
  }

  // ---- init c (registers, replicated across quad) ----
  float creg[2][4];
  #pragma unroll
  for (int mf = 0; mf < 2; ++mf)
    #pragma unroll
    for (int r = 0; r < 4; ++r) {
      int b = mf * 16 + (l >> 4) * 4 + r;
      creg[mf][r] = a.c_init_bcast ? a.c_init_bcast[col]
                                   : a.c_init_elem[b * HH + col];
    }
  __syncthreads();

  int prow0 = tid >> 7;      // 0 or 1: this thread's first packet row
  int pcp4 = tid & 127;      // fixed column-group (one producer: pcp4>>2)

  // prefetch xw slice for first step
  int s0i = a.backward ? (a.steps - 1) : 0;
  float4 xcur = *(const float4*)(a.xw + ((size_t)s0i * 32 + cblk) * 2048 + tid * 8);
  float4 xnext;

  for (int it = 0; it < a.steps; ++it) {
    int s = a.backward ? (a.steps - 1 - it) : it;
    const uint* hsrc = a.hpack + (size_t)(it & 1) * 4096 * 4;
    uint* hdst = a.hpack + (size_t)((it + 1) & 1) * 4096 * 4;

    // ---- batch-load own packets; batch re-poll rounds until tag == it ----
    u32x4 pv[16];
    #pragma unroll
    for (int j = 0; j < 16; ++j) {
      const uint* ap = hsrc + (size_t)((prow0 + 2 * j) * 128 + pcp4) * 4;
      asm volatile("global_load_dwordx4 %0, %1, off sc0 sc1"
                   : "=&v"(pv[j]) : "v"(ap) : "memory");
    }
    asm volatile("s_waitcnt vmcnt(0)" ::: "memory");
    __builtin_amdgcn_sched_barrier(0);
    {
      int guard = 0;
      while (true) {
        uint bad = 0;
        #pragma unroll
        for (int j = 0; j < 16; ++j) bad |= (pv[j][2] ^ (uint)it);
        if (bad == 0) break;
        if (++guard > (1 << 18)) break;   // fail loud, never hang
        __builtin_amdgcn_s_sleep(1);
        #pragma unroll
        for (int j = 0; j < 16; ++j) {
          const uint* ap = hsrc + (size_t)((prow0 + 2 * j) * 128 + pcp4) * 4;
          asm volatile("global_load_dwordx4 %0, %1, off sc0 sc1"
                       : "=&v"(pv[j]) : "v"(ap) : "memory");
        }
        asm volatile("s_waitcnt vmcnt(0)" ::: "memory");
        __builtin_amdgcn_sched_barrier(0);
      }
    }
    __syncthreads();                      // A: prior iter's LDS readers done

    // ---- stage h into swizzled LDS (8B per packet) + xw ----
    #pragma unroll
    for (int j = 0; j < 16; ++j) {
      int row = prow0 + 2 * j;
      int byte = (row * 1024 + pcp4 * 8) ^ ((row & 7) << 4);
      *(u64t*)((char*)ldsH + byte) = ((u64t)pv[j][1] << 32) | (u64t)pv[j][0];
    }
    *(float4*)&ldsX[tid * 8] = xcur;
    __syncthreads();                      // B: staging visible

    // ---- MFMA: 2 M-tiles x 1 N-tile x 16 K-steps ----
    f32x4 acc0 = (f32x4){0.f, 0.f, 0.f, 0.f};
    f32x4 acc1 = (f32x4){0.f, 0.f, 0.f, 0.f};
    #pragma unroll
    for (int k0 = 0; k0 < HH; k0 += 32) {
      int ka = k0 + kb;
      bf16x8t av0 = *(const bf16x8t*)((const char*)ldsH + ((lr * 1024 + ka * 2) ^ ((lr & 7) << 4)));
      bf16x8t av1 = *(const bf16x8t*)((const char*)ldsH + (((16 + lr) * 1024 + ka * 2) ^ (((16 + lr) & 7) << 4)));
      int wr = w * 16 + lr;
      bf16x8t bv = *(const bf16x8t*)((const char*)ldsW + ((wr * 1024 + ka * 2) ^ ((wr & 7) << 4)));
      acc0 = __builtin_amdgcn_mfma_f32_16x16x32_bf16(av0, bv, acc0, 0, 0, 0);
      acc1 = __builtin_amdgcn_mfma_f32_16x16x32_bf16(av1, bv, acc1, 0, 0, 0);
    }

    // ---- gates: quad-parallel activation, then exchange; pack 4 cols ----
    u64t pk[2][4];
    #pragma unroll
    for (int mf = 0; mf < 2; ++mf) {
      f32x4 ac = mf ? acc1 : acc0;
      #pragma unroll
      for (int r = 0; r < 4; ++r) {
        int b = mf * 16 + (l >> 4) * 4 + r;
        float v = ac[r] + bf2f(ldsX[b * 64 + n]);
        float av = (g == 2) ? ftanh(v) : fsigmoid(v);
        float a1 = __shfl_xor(av, 1);
        float a2 = __shfl_xor(av, 2);
        float a3 = __shfl_xor(av, 3);
        float hnew = 0.f;
        if (g == 0) {
          float iv = av, fv = a1, gv = a2, ov = a3;
          float cnew = fv * creg[mf][r] + iv * gv;
          hnew = ov * ftanh(cnew);
          creg[mf][r] = cnew;
          if (a.h_final && it == a.steps - 1) {
            a.h_final[b * HH + col] = hnew;
            a.c_final[b * HH + col] = cnew;
          }
        }
        uint hu = (uint)f2bf(hnew);
        uint p1 = __shfl_xor(hu, 4);
        uint p2 = __shfl_xor(hu, 8);
        uint p3 = __shfl_xor(p1, 8);
        uint lo = hu | (p1 << 16);
        uint hi = p2 | (p3 << 16);
        pk[mf][r] = ((u64t)hi << 32) | (u64t)lo;
      }
    }

    // ---- packet stores: single dwordx4 each, fire & forget ----
    if ((l & 15) == 0 && it + 1 < a.steps) {
      int cp4w = cblk * 4 + w;
      #pragma unroll
      for (int mf = 0; mf < 2; ++mf)
        #pragma unroll
        for (int r = 0; r < 4; ++r) {
          int b = mf * 16 + (l >> 4) * 4 + r;
          u32x4 pkt;
          pkt[0] = (uint)pk[mf][r];
          pkt[1] = (uint)(pk[mf][r] >> 32);
          pkt[2] = (uint)(it + 1);
          pkt[3] = 0u;
          uint* dp = hdst + (size_t)(b * 128 + cp4w) * 4;
          asm volatile("global_store_dwordx4 %0, %1, off sc0 sc1"
                       :: "v"(dp), "v"(pkt) : "memory");
        }
    }

    // ---- off critical path: out_h stores + next xw prefetch ----
    if ((l & 15) == 0) {
      #pragma unroll
      for (int mf = 0; mf < 2; ++mf)
        #pragma unroll
        for (int r = 0; r < 4; ++r) {
          int b = mf * 16 + (l >> 4) * 4 + r;
          *(u64t*)(a.out_h + (size_t)s * BB * a.out_os + b * a.out_os +
                   a.out_ofs + c0 + w * 4) = pk[mf][r];
        }
    }
    if (it + 1 < a.steps) {
      int sn = a.backward ? (a.steps - 2 - it) : (it + 1);
      const ushort* xp = a.xw + ((size_t)sn * 32 + cblk) * 2048 + tid * 8;
      asm volatile("global_load_dwordx4 %0, %1, off"
                   : "=&v"(xnext) : "v"(xp) : "memory");
    }
    xcur = xnext;
  }
}

// ---------------------------------------------------------------------------
// decoder init: dh packets (tag 0, slot 0) + dc fp32
// ---------------------------------------------------------------------------
__global__ __launch_bounds__(256) void dec_init_kernel(
    const float* __restrict__ hf, const float* __restrict__ hb,
    const float* __restrict__ cf, const float* __restrict__ cb,
    const float* __restrict__ Wh, const float* __restrict__ Wc,
    uint* __restrict__ dh_pack, float* __restrict__ dc)
{
  int b = blockIdx.x;
  __shared__ float hcat[2 * HH], ccat[2 * HH];
  __shared__ ushort dhs[HH];
  int tid = threadIdx.x;
  for (int i = tid; i < HH; i += 256) {
    hcat[i] = hf[b * HH + i]; hcat[HH + i] = hb[b * HH + i];
    ccat[i] = cf[b * HH + i]; ccat[HH + i] = cb[b * HH + i];
  }
  __syncthreads();
  for (int col = tid; col < HH; col += 256) {
    const float4* wh = (const float4*)(Wh + (size_t)col * (2 * HH));
    const float4* wc = (const float4*)(Wc + (size_t)col * (2 * HH));
    float ah = 0.f, acv = 0.f;
    #pragma unroll 4
    for (int k4 = 0; k4 < (2 * HH) / 4; ++k4) {
      float4 h4 = *(const float4*)&hcat[k4 * 4];
      float4 w4 = wh[k4];
      ah += h4.x * w4.x + h4.y * w4.y + h4.z * w4.z + h4.w * w4.w;
      float4 c4 = *(const float4*)&ccat[k4 * 4];
      float4 v4 = wc[k4];
      acv += c4.x * v4.x + c4.y * v4.y + c4.z * v4.z + c4.w * v4.w;
    }
    dhs[col] = f2bf(ah);
    dc[b * HH + col] = acv;
  }
  __syncthreads();
  if (tid < 128) {
    int c = tid * 4;
    uint lo = (uint)dhs[c] | ((uint)dhs[c + 1] << 16);
    uint hi = (uint)dhs[c + 2] | ((uint)dhs[c + 3] << 16);
    u32x4 pkt = {lo, hi, 0u, 0u};
    *(u32x4*)(dh_pack + (size_t)(b * 128 + tid) * 4) = pkt;
  }
}

// ---------------------------------------------------------------------------
__global__ __launch_bounds__(256) void scores_kernel(
    const ushort* __restrict__ keys_bf, const ushort* __restrict__ dhall,
    const int* __restrict__ slen, float* __restrict__ sc)
{
  int b = blockIdx.x & 31, s0 = ((int)blockIdx.x >> 5) * 16;
  __shared__ ushort ldsD[64][520];
  __shared__ ushort ldsK[16][520];
  int tid = threadIdx.x;
  #pragma unroll
  for (int j = 0; j < 16; ++j) {
    int ci = tid + 256 * j;
    int row = ci >> 6, c8 = (ci & 63) * 8;
    *(u16x8*)&ldsD[row][c8] = *(const u16x8*)(dhall + ((size_t)row * BB + b) * HH + c8);
  }
  #pragma unroll
  for (int j = 0; j < 4; ++j) {
    int ci = tid + 256 * j;
    int row = ci >> 6, c8 = (ci & 63) * 8;
    *(u16x8*)&ldsK[row][c8] = *(const u16x8*)(keys_bf + ((size_t)(s0 + row) * BB + b) * HH + c8);
  }
  __syncthreads();

  int sl = tid & 15, tq = tid >> 4;
  float acc[4] = {0.f, 0.f, 0.f, 0.f};
  for (int k8 = 0; k8 < 64; ++k8) {
    float kv[8];
    unpack8(*(const uint4*)&ldsK[sl][k8 * 8], kv);
    #pragma unroll
    for (int j = 0; j < 4; ++j) {
      float dv[8];
      unpack8(*(const uint4*)&ldsD[tq * 4 + j][k8 * 8], dv);
      #pragma unroll
      for (int e = 0; e < 8; ++e) acc[j] += kv[e] * dv[e];
    }
  }
  int s = s0 + sl;
  int len = slen[b];
  #pragma unroll
  for (int j = 0; j < 4; ++j) {
    int t = tq * 4 + j;
    sc[((size_t)t * BB + b) * SS + s] = (s < len) ? acc[j] : -1e18f;
  }
}

__global__ __launch_bounds__(64) void softmax_kernel(
    const float* __restrict__ sc, ushort* __restrict__ wbf)
{
  int row = blockIdx.x;
  int tid = threadIdx.x;
  float v[7];
  float m = -3e38f;
  #pragma unroll
  for (int j = 0; j < 7; ++j) {
    int s = tid + 64 * j;
    v[j] = (s < SS) ? sc[(size_t)row * SS + s] : -3e38f;
    m = fmaxf(m, v[j]);
  }
  #pragma unroll
  for (int o = 32; o; o >>= 1) m = fmaxf(m, __shfl_xor(m, o));
  float ssum = 0.f;
  float p[7];
  #pragma unroll
  for (int j = 0; j < 7; ++j) {
    int s = tid + 64 * j;
    p[j] = (s < SS) ? __expf(v[j] - m) : 0.f;
    ssum += p[j];
  }
  #pragma unroll
  for (int o = 32; o; o >>= 1) ssum += __shfl_xor(ssum, o);
  float inv = 1.f / ssum;
  #pragma unroll
  for (int j = 0; j < 7; ++j) {
    int s = tid + 64 * j;
    if (s < 416) wbf[(size_t)row * 416 + s] = (s < SS) ? f2bf(p[j] * inv) : (ushort)0;
  }
}

// ---------------------------------------------------------------------------
__global__ __launch_bounds__(256) void context_kernel(
    const ushort* __restrict__ wbf, const ushort* __restrict__ enc,
    const ushort* __restrict__ dhall, ushort* __restrict__ catb)
{
  int b = blockIdx.x, ch = blockIdx.y;
  int tid = threadIdx.x;
  if (ch >= 16) {
    int c0 = (ch - 16) * 64;
    #pragma unroll
    for (int j = 0; j < 2; ++j) {
      int ci = tid + 256 * j;
      int t = ci >> 3, u = ci & 7;
      *(u16x8*)(catb + ((size_t)t * BB + b) * 1536 + 1024 + c0 + u * 8) =
          *(const u16x8*)(dhall + ((size_t)t * BB + b) * HH + c0 + u * 8);
    }
    return;
  }
  int d0 = ch * 64;
  __shared__ ushort ldsWt[64][424];
  for (int ci = tid; ci < 64 * 52; ci += 256) {
    int t = ci / 52, u = ci % 52;
    *(u16x8*)&ldsWt[t][u * 8] = *(const u16x8*)(wbf + (size_t)(t * BB + b) * 416 + u * 8);
  }
  __syncthreads();

  int d = d0 + (tid & 63), tq = tid >> 6;
  float acc16[16];
  #pragma unroll
  for (int i = 0; i < 16; ++i) acc16[i] = 0.f;

  for (int s8 = 0; s8 < 50; ++s8) {
    float ev[8];
    #pragma unroll
    for (int e = 0; e < 8; ++e)
      ev[e] = bf2f(enc[((size_t)(s8 * 8 + e) * BB + b) * 1024 + d]);
    #pragma unroll
    for (int i = 0; i < 16; ++i) {
      float wv[8];
      unpack8(*(const uint4*)&ldsWt[tq * 16 + i][s8 * 8], wv);
      #pragma unroll
      for (int e = 0; e < 8; ++e) acc16[i] += wv[e] * ev[e];
    }
  }
  #pragma unroll
  for (int i = 0; i < 16; ++i) {
    int t = tq * 16 + i;
    catb[((size_t)t * BB + b) * 1536 + d] = f2bf(acc16[i]);
  }
}

// ---------------------------------------------------------------------------
__global__ __launch_bounds__(1024) void logsoftmax_kernel(float* __restrict__ out)
{
  int r = blockIdx.x;
  __shared__ float row[VV];
  __shared__ float red[16];
  int tid = threadIdx.x;
  float4* p = (float4*)(out + (size_t)r * VV);
  float4* rp = (float4*)row;
  float m = -3e38f;
  #pragma unroll
  for (int j = 0; j < 8; ++j) {
    int i = tid + 1024 * j;
    if (i < VV / 4) {
      float4 v = p[i];
      rp[i] = v;
      m = fmaxf(m, fmaxf(fmaxf(v.x, v.y), fmaxf(v.z, v.w)));
    }
  }
  #pragma unroll
  for (int o = 32; o; o >>= 1) m = fmaxf(m, __shfl_xor(m, o));
  if ((tid & 63) == 0) red[tid >> 6] = m;
  __syncthreads();
  float mm = red[0];
  #pragma unroll
  for (int i = 1; i < 16; ++i) mm = fmaxf(mm, red[i]);
  __syncthreads();
  float ssum = 0.f;
  #pragma unroll
  for (int j = 0; j < 8; ++j) {
    int i = tid + 1024 * j;
    if (i < VV / 4) {
      float4 v = rp[i];
      ssum += __expf(v.x - mm) + __expf(v.y - mm) + __expf(v.z - mm) + __expf(v.w - mm);
    }
  }
  #pragma unroll
  for (int o = 32; o; o >>= 1) ssum += __shfl_xor(ssum, o);
  if ((tid & 63) == 0) red[tid >> 6] = ssum;
  __syncthreads();
  float st = red[0];
  #pragma unroll
  for (int i = 1; i < 16; ++i) st += red[i];
  st = mm + logf(st);
  #pragma unroll
  for (int j = 0; j < 8; ++j) {
    int i = tid + 1024 * j;
    if (i < VV / 4) {
      float4 v = rp[i];
      v.x -= st; v.y -= st; v.z -= st; v.w -= st;
      p[i] = v;
    }
  }
}

// ---------------------------------------------------------------------------
extern "C" void kernel_launch(void* const* d_in, const int* in_sizes, int n_in,
                              void* d_out, int out_size, void* d_ws, size_t ws_size,
                              hipStream_t stream)
{
  (void)in_sizes; (void)n_in; (void)out_size; (void)ws_size;
  const int*   src  = (const int*)d_in[0];
  const int*   slen = (const int*)d_in[1];
  const int*   tgt  = (const int*)d_in[2];
  const float* emb  = (const float*)d_in[3];
  const float* eWif = (const float*)d_in[4];
  const float* eWhf = (const float*)d_in[5];
  const float* ebif = (const float*)d_in[6];
  const float* ebhf = (const float*)d_in[7];
  const float* eWib = (const float*)d_in[8];
  const float* eWhb = (const float*)d_in[9];
  const float* ebib = (const float*)d_in[10];
  const float* ebhb = (const float*)d_in[11];
  const float* einh = (const float*)d_in[12];
  const float* einc = (const float*)d_in[13];
  const float* dhW  = (const float*)d_in[14];
  const float* dcW  = (const float*)d_in[15];
  const float* cWi  = (const float*)d_in[16];
  const float* cWh  = (const float*)d_in[17];
  const float* cbi  = (const float*)d_in[18];
  const float* cbh  = (const float*)d_in[19];
  const float* aW   = (const float*)d_in[20];
  const float* abv  = (const float*)d_in[21];
  const float* ccW  = (const float*)d_in[22];
  const float* ccbv = (const float*)d_in[23];
  const float* oW   = (const float*)d_in[24];
  const float* obv  = (const float*)d_in[25];
  float* out = (float*)d_out;
  float* ws  = (float*)d_ws;

  // ---------- workspace layout (float units) ----------
  size_t off = 0;
  ushort* enc_bf  = (ushort*)(ws + off); off += (size_t)SS * BB * 1024 / 2;
  ushort* keys_bf = (ushort*)(ws + off); off += (size_t)SS * BB * HH / 2;
  ushort* dhall_bf= (ushort*)(ws + off); off += (size_t)TT * BB * HH / 2;
  ushort* catb_bf = (ushort*)(ws + off); off += (size_t)TT * BB * 1536 / 2;
  ushort* ccv_bf  = (ushort*)(ws + off); off += (size_t)TT * BB * HH / 2;
  float*  scbuf   = ws + off;            off += (size_t)TT * BB * SS;
  ushort* w_bf    = (ushort*)(ws + off); off += (size_t)TT * BB * 416 / 2;
  ushort* xe_bf   = (ushort*)(ws + off); off += (size_t)SS * BB * EE / 2;
  ushort* xd_bf   = (ushort*)(ws + off); off += (size_t)TT * BB * EE / 2;
  ushort* xWf_bf  = (ushort*)(ws + off); off += (size_t)SS * BB * 2048 / 2;
  ushort* xWb_bf  = (ushort*)(ws + off); off += (size_t)SS * BB * 2048 / 2;
  ushort* xWd_bf  = (ushort*)(ws + off); off += (size_t)TT * BB * 2048 / 2;
  ushort* oW_bf   = (ushort*)(ws + off); off += (size_t)VV * HH / 2;
  ushort* aW_bf   = (ushort*)(ws + off); off += (size_t)HH * 1024 / 2;
  ushort* ccW_bf  = (ushort*)(ws + off); off += (size_t)HH * 1536 / 2;
  ushort* eWif_bf = (ushort*)(ws + off); off += (size_t)2048 * EE / 2;
  ushort* eWib_bf = (ushort*)(ws + off); off += (size_t)2048 * EE / 2;
  ushort* cWi_bf  = (ushort*)(ws + off); off += (size_t)2048 * EE / 2;
  // packet buffers: [2 slots][32 b][128 cp4] x 16B each; contiguous for memset
  uint* hge_pack = (uint*)(ws + off); off += (size_t)2 * 4096 * 4;
  uint* hgb_pack = (uint*)(ws + off); off += (size_t)2 * 4096 * 4;
  uint* hdec_pack= (uint*)(ws + off); off += (size_t)2 * 4096 * 4;
  float* bias3 = ws + off; off += 3 * 2048;
  float* hf_f  = ws + off; off += BB * HH;
  float* hb_f  = ws + off; off += BB * HH;
  float* cf_f  = ws + off; off += BB * HH;
  float* cb_f  = ws + off; off += BB * HH;
  float* dcb   = ws + off; off += BB * HH;

  // 0. zero packet buffers (tags) -- protects the first (unpoisoned) call
  hipMemsetAsync(hge_pack, 0, (size_t)3 * 2 * 4096 * 16, stream);

  // 1. initial-h packets for encoder
  init_all_kernel<<<64, 256, 0, stream>>>(einh, hge_pack, hgb_pack);

  // 2. weight conversions (oW/aW/ccW + xWd GEMM folded into encoder below)
  f2bf_kernel<<<512, 256, 0, stream>>>(eWif, eWif_bf, (long)2048 * EE);
  f2bf_kernel<<<512, 256, 0, stream>>>(eWib, eWib_bf, (long)2048 * EE);
  f2bf_kernel<<<512, 256, 0, stream>>>(cWi, cWi_bf, (long)2048 * EE);
  bias3_kernel<<<24, 256, 0, stream>>>(ebif, ebhf, ebib, ebhb, cbi, cbh, bias3);

  // 3. x gathers + encoder xW GEMMs (bias folded, xw-layout bf16 out)
  gather_x_kernel<<<SS * BB, 64, 0, stream>>>(emb, src, SS, xe_bf);
  gather_x_kernel<<<TT * BB, 64, 0, stream>>>(emb, tgt, TT, xd_bf);
  gemm_mfma_kernel<<<dim3(2048 / 128, (SS * BB) / 128), 256, 0, stream>>>(
      xe_bf, eWif_bf, bias3, xWf_bf, SS * BB, 2048, EE, 8);
  gemm_mfma_kernel<<<dim3(2048 / 128, (SS * BB) / 128), 256, 0, stream>>>(
      xe_bf, eWib_bf, bias3 + 2048, xWb_bf, SS * BB, 2048, EE, 8);

  // 4. persistent bi-encoder (400 steps) + aux: xWd GEMM then conversions
  {
    PersistArgs af, ab;
    af.W_hh = eWhf; af.xw = xWf_bf; af.hpack = hge_pack;
    af.c_init_elem = nullptr; af.c_init_bcast = einc;
    af.out_h = enc_bf; af.out_os = 1024; af.out_ofs = 0;
    af.steps = SS; af.backward = 0;
    af.h_final = hf_f; af.c_final = cf_f;
    ab = af;
    ab.W_hh = eWhb; ab.xw = xWb_bf; ab.hpack = hgb_pack;
    ab.c_init_bcast = einc + HH;
    ab.out_ofs = HH; ab.backward = 1;
    ab.h_final = hb_f; ab.c_final = cb_f;
    CvtJobs cv;
    cv.in0 = oW;  cv.out0 = oW_bf;  cv.n0 = (long)VV * HH;
    cv.in1 = aW;  cv.out1 = aW_bf;  cv.n1 = (long)HH * 1024;
    cv.in2 = ccW; cv.out2 = ccW_bf; cv.n2 = (long)HH * 1536;
    AuxGemm ag;
    ag.A = xd_bf; ag.B = cWi_bf; ag.bias = bias3 + 4096; ag.C = xWd_bf;
    ag.M = TT * BB; ag.N = 2048; ag.K = EE; ag.flags = 8;
    lstm_persist_kernel<<<256, 256, 0, stream>>>(af, ab, 32, 64, cv, ag);
  }

  // 5. decoder init + persistent decoder (64 steps, no aux -- R14 lesson)
  dec_init_kernel<<<BB, 256, 0, stream>>>(hf_f, hb_f, cf_f, cb_f, dhW, dcW,
                                          hdec_pack, dcb);
  {
    PersistArgs ad;
    ad.W_hh = cWh; ad.xw = xWd_bf; ad.hpack = hdec_pack;
    ad.c_init_elem = dcb; ad.c_init_bcast = nullptr;
    ad.out_h = dhall_bf; ad.out_os = HH; ad.out_ofs = 0;
    ad.steps = TT; ad.backward = 0;
    ad.h_final = nullptr; ad.c_final = nullptr;
    CvtJobs cv;
    cv.in0 = nullptr; cv.out0 = nullptr; cv.n0 = 0;
    cv.in1 = nullptr; cv.out1 = nullptr; cv.n1 = 0;
    cv.in2 = nullptr; cv.out2 = nullptr; cv.n2 = 0;
    AuxGemm ag; ag.A = nullptr; ag.B = nullptr; ag.bias = nullptr;
    ag.C = nullptr; ag.M = 0; ag.N = 0; ag.K = 0; ag.flags = 0;
    lstm_persist_kernel<<<32, 256, 0, stream>>>(ad, ad, 32, 32, cv, ag);
  }

  // 6. attention keys GEMM (standalone, full GPU)
  gemm_mfma_kernel<<<dim3(HH / 128, (SS * BB) / 128), 256, 0, stream>>>(
      enc_bf, aW_bf, abv, keys_bf, SS * BB, HH, 1024, 4);

  // 7. attention: scores -> softmax -> context/copy
  scores_kernel<<<32 * 25, 256, 0, stream>>>(keys_bf, dhall_bf, slen, scbuf);
  softmax_kernel<<<TT * BB, 64, 0, stream>>>(scbuf, w_bf);
  context_kernel<<<dim3(BB, 24), 256, 0, stream>>>(w_bf, enc_bf, dhall_bf, catb_bf);

  // 8. concat + output GEMMs
  gemm_mfma_kernel<<<dim3(HH / 128, (TT * BB) / 128), 256, 0, stream>>>(
      catb_bf, ccW_bf, ccbv, ccv_bf, TT * BB, HH, 1536, 1 | 4);
  gemm_mfma_kernel<<<dim3(VV / 128, (TT * BB) / 128), 256, 0, stream>>>(
      ccv_bf, oW_bf, obv, out, TT * BB, VV, HH, 2);

  // 9. fused log-softmax
  logsoftmax_kernel<<<TT * BB, 1024, 0, stream>>>(out);
}

// Round 16
// 2965.970 us; speedup vs baseline: 1.0845x; 1.0845x over previous
//
#include <hip/hip_runtime.h>
#include <math.h>

#define BB 32
#define SS 400
#define TT 64
#define VV 32000
#define EE 256
#define HH 512

typedef __attribute__((ext_vector_type(4))) float f32x4;
typedef __attribute__((ext_vector_type(8))) short bf16x8t;
typedef __attribute__((ext_vector_type(8))) unsigned short u16x8;
typedef __attribute__((ext_vector_type(4))) unsigned int u32x4;
typedef unsigned long long u64t;

__device__ __forceinline__ ushort f2bf(float x) {
  uint u = __float_as_uint(x);
  return (ushort)((u + 0x7fffu + ((u >> 16) & 1u)) >> 16);
}
__device__ __forceinline__ float bf2f(ushort x) {
  return __uint_as_float(((uint)x) << 16);
}
__device__ __forceinline__ float fsigmoid(float x) {
  return 1.f / (1.f + __expf(-x));
}
__device__ __forceinline__ float ftanh(float x) {
  return 1.f - 2.f / (__expf(2.f * x) + 1.f);
}
__device__ __forceinline__ void gload_lds16(const ushort* g, ushort* l) {
  __builtin_amdgcn_global_load_lds(
      (const __attribute__((address_space(1))) void*)g,
      (__attribute__((address_space(3))) void*)l, 16, 0, 0);
}
__device__ __forceinline__ void unpack8(uint4 u, float* f) {
  f[0] = __uint_as_float(u.x << 16); f[1] = __uint_as_float(u.x & 0xffff0000u);
  f[2] = __uint_as_float(u.y << 16); f[3] = __uint_as_float(u.y & 0xffff0000u);
  f[4] = __uint_as_float(u.z << 16); f[5] = __uint_as_float(u.z & 0xffff0000u);
  f[6] = __uint_as_float(u.w << 16); f[7] = __uint_as_float(u.w & 0xffff0000u);
}

// ---------------------------------------------------------------------------
// init: write initial-h packets (tag 0, slot 0) for both encoder directions
// ---------------------------------------------------------------------------
__global__ __launch_bounds__(256) void init_all_kernel(
    const float* __restrict__ einh, uint* __restrict__ hge,
    uint* __restrict__ hgb)
{
  int i = blockIdx.x * 256 + threadIdx.x;
  if (i < 4096) {
    int c = (i & 127) * 4;
    uint lo = (uint)f2bf(einh[c]) | ((uint)f2bf(einh[c + 1]) << 16);
    uint hi = (uint)f2bf(einh[c + 2]) | ((uint)f2bf(einh[c + 3]) << 16);
    u32x4 pkt = {lo, hi, 0u, 0u};
    *(u32x4*)(hge + (size_t)i * 4) = pkt;
  } else if (i < 8192) {
    int p = i - 4096;
    int c = HH + (p & 127) * 4;
    uint lo = (uint)f2bf(einh[c]) | ((uint)f2bf(einh[c + 1]) << 16);
    uint hi = (uint)f2bf(einh[c + 2]) | ((uint)f2bf(einh[c + 3]) << 16);
    u32x4 pkt = {lo, hi, 0u, 0u};
    *(u32x4*)(hgb + (size_t)p * 4) = pkt;
  }
}

__global__ __launch_bounds__(256) void f2bf_kernel(
    const float* __restrict__ in, ushort* __restrict__ out, long n)
{
  long step = (long)gridDim.x * 256 * 4;
  for (long i = ((long)blockIdx.x * 256 + threadIdx.x) * 4; i < n; i += step) {
    float4 v = *(const float4*)(in + i);
    ushort4 o;
    o.x = f2bf(v.x); o.y = f2bf(v.y); o.z = f2bf(v.z); o.w = f2bf(v.w);
    *(ushort4*)(out + i) = o;
  }
}

// gather emb rows (fp32 src) -> bf16 x rows: row = s*32+b
__global__ __launch_bounds__(64) void gather_x_kernel(
    const float* __restrict__ emb, const int* __restrict__ tok, int L,
    ushort* __restrict__ xout)
{
  int row = blockIdx.x;
  int b = row & 31, s = row >> 5;
  int t = tok[b * L + s];
  float4 v = ((const float4*)(emb + (size_t)t * EE))[threadIdx.x];
  ushort4 o;
  o.x = f2bf(v.x); o.y = f2bf(v.y); o.z = f2bf(v.z); o.w = f2bf(v.w);
  ((ushort4*)(xout + (size_t)row * EE))[threadIdx.x] = o;
}

__global__ __launch_bounds__(256) void bias3_kernel(
    const float* a1, const float* a2, const float* b1, const float* b2,
    const float* c1, const float* c2, float* out)
{
  int i = blockIdx.x * 256 + threadIdx.x;
  if (i < 2048) out[i] = a1[i] + a2[i];
  else if (i < 4096) out[i] = b1[i - 2048] + b2[i - 2048];
  else if (i < 6144) out[i] = c1[i - 4096] + c2[i - 4096];
}

// ---------------------------------------------------------------------------
// bf16 MFMA GEMM: C[M,N] = act(A[M,K] @ B[N,K]^T + bias)
// flags: 1=tanh, 2=row remap (t*32+b)->(b*TT+t), 4=bf16 out, 8=xw-layout out
// ---------------------------------------------------------------------------
__global__ __launch_bounds__(256) void gemm_mfma_kernel(
    const ushort* __restrict__ A, const ushort* __restrict__ B,
    const float* __restrict__ bias, void* __restrict__ Cout,
    int M, int N, int K, int flags)
{
  __shared__ ushort Asub[128 * 32], Bsub[128 * 32];
  int tid = threadIdx.x;
  int w = tid >> 6, l = tid & 63;
  int n0 = blockIdx.x * 128, m0 = blockIdx.y * 128;
  int wm = w >> 1, wn = w & 1;

  int srow = 16 * 2 * w + (l >> 2);
  int scol = (l & 3) * 8;
  const ushort* Ar0 = A + (size_t)(m0 + srow) * K + scol;
  const ushort* Ar1 = Ar0 + (size_t)16 * K;
  const ushort* Br0 = B + (size_t)(n0 + srow) * K + scol;
  const ushort* Br1 = Br0 + (size_t)16 * K;
  ushort* ldsA0 = Asub + (2 * w) * 512;
  ushort* ldsA1 = Asub + (2 * w + 1) * 512;
  ushort* ldsB0 = Bsub + (2 * w) * 512;
  ushort* ldsB1 = Bsub + (2 * w + 1) * 512;

  f32x4 acc[4][4];
  #pragma unroll
  for (int i = 0; i < 4; ++i)
    #pragma unroll
    for (int j = 0; j < 4; ++j)
      acc[i][j] = (f32x4){0.f, 0.f, 0.f, 0.f};

  int lr = l & 15, lkb = (l >> 4) * 8;

  for (int k0 = 0; k0 < K; k0 += 32) {
    gload_lds16(Ar0 + k0, ldsA0);
    gload_lds16(Ar1 + k0, ldsA1);
    gload_lds16(Br0 + k0, ldsB0);
    gload_lds16(Br1 + k0, ldsB1);
    __syncthreads();
    bf16x8t af[4], bfv[4];
    #pragma unroll
    for (int mf = 0; mf < 4; ++mf)
      af[mf] = *(const bf16x8t*)&Asub[(wm * 64 + mf * 16 + lr) * 32 + lkb];
    #pragma unroll
    for (int nf = 0; nf < 4; ++nf)
      bfv[nf] = *(const bf16x8t*)&Bsub[(wn * 64 + nf * 16 + lr) * 32 + lkb];
    #pragma unroll
    for (int mf = 0; mf < 4; ++mf)
      #pragma unroll
      for (int nf = 0; nf < 4; ++nf)
        acc[mf][nf] = __builtin_amdgcn_mfma_f32_16x16x32_bf16(
            af[mf], bfv[nf], acc[mf][nf], 0, 0, 0);
    __syncthreads();
  }

  int lg = l >> 4;
  #pragma unroll
  for (int mf = 0; mf < 4; ++mf) {
    #pragma unroll
    for (int nf = 0; nf < 4; ++nf) {
      int n = n0 + wn * 64 + nf * 16 + lr;
      float bv = bias[n];
      #pragma unroll
      for (int r = 0; r < 4; ++r) {
        int m = m0 + wm * 64 + mf * 16 + lg * 4 + r;
        float v = acc[mf][nf][r] + bv;
        if (flags & 1) v = tanhf(v);
        if (flags & 8) {
          int s = m >> 5, b = m & 31;
          int gate = n >> 9, col = n & 511;
          size_t dst = (((size_t)s * 32 + (col >> 4)) * 32 + b) * 64 +
                       (size_t)(col & 15) * 4 + gate;
          ((ushort*)Cout)[dst] = f2bf(v);
        } else {
          int row = (flags & 2) ? ((m & 31) * TT + (m >> 5)) : m;
          if (flags & 4) ((ushort*)Cout)[(size_t)row * N + n] = f2bf(v);
          else           ((float*)Cout)[(size_t)row * N + n] = v;
        }
      }
    }
  }
}

// ---------------------------------------------------------------------------
// Persistent LSTM with tag-in-data packets (R10/R13-proven protocol).
// W fragments preloaded into registers (time-invariant, 16x bf16x8/thread):
// MFMA loop is register-only for the B operand -- no per-step ldsW reads.
// Blocks >= 2*nblk_dir convert cvt_in->bf16 (folded into the shadow).
// ---------------------------------------------------------------------------
struct PersistArgs {
  const float* W_hh;
  const ushort* xw;          // [steps][32 cblk][32 b][64] bf16
  uint* hpack;               // [2 slots][32 b][128 cp4] 16B packets
  const float* c_init_elem;  // [32][512] fp32 or null
  const float* c_init_bcast; // [512] fp32 or null
  ushort* out_h;             // [steps][32][OS] bf16
  int out_os, out_ofs;
  int steps, backward;
  float* h_final;            // [32][512] fp32 or null
  float* c_final;
};

__global__ __launch_bounds__(256) void lstm_persist_kernel(
    PersistArgs A0, PersistArgs A1, int nblk_dir,
    const float* __restrict__ cvt_in, ushort* __restrict__ cvt_out, long cvt_n)
{
  __shared__ ushort ldsW[64 * 512];
  __shared__ ushort ldsH[32 * 512];
  __shared__ ushort ldsX[32 * 64];

  int bid = (int)blockIdx.x;
  if (bid >= 2 * nblk_dir) {
    // -------- converter block: f2bf over cvt_in (runs in encoder shadow) ----
    int nc = (int)gridDim.x - 2 * nblk_dir;
    long base = ((long)(bid - 2 * nblk_dir) * 256 + threadIdx.x) * 4;
    long step = (long)nc * 256 * 4;
    for (long i = base; i < cvt_n; i += step) {
      float4 v = *(const float4*)(cvt_in + i);
      ushort4 o;
      o.x = f2bf(v.x); o.y = f2bf(v.y); o.z = f2bf(v.z); o.w = f2bf(v.w);
      *(ushort4*)(cvt_out + i) = o;
    }
    return;
  }

  PersistArgs a = (bid < nblk_dir) ? A0 : A1;
  int cblk = bid % nblk_dir;
  int c0 = cblk * 16;
  int tid = threadIdx.x;
  int w = tid >> 6, l = tid & 63;
  int lr = l & 15, kb = (l >> 4) * 8;
  int g = l & 3;
  int col = c0 + w * 4 + (lr >> 2);
  int n = w * 16 + lr;

  // ---- stage W slice (once), swizzled bf16 ----
  {
    int nn = tid >> 2;                   // 0..63
    int kbase = (tid & 3) * 128;
    int rW = (nn & 3) * HH + c0 + (nn >> 2);
    const float4* src = (const float4*)(a.W_hh + (size_t)rW * HH + kbase);
    #pragma unroll
    for (int j = 0; j < 16; ++j) {
      float4 u = src[2 * j], v = src[2 * j + 1];
      u16x8 o;
      o[0] = f2bf(u.x); o[1] = f2bf(u.y); o[2] = f2bf(u.z); o[3] = f2bf(u.w);
      o[4] = f2bf(v.x); o[5] = f2bf(v.y); o[6] = f2bf(v.z); o[7] = f2bf(v.w);
      int k = kbase + j * 8;
      int byte = (nn * 1024 + k * 2) ^ ((nn & 7) << 4);
      *(u16x8*)((char*)ldsW + byte) = o;
    }
  }

  // ---- init c (registers, replicated across quad) ----
  float creg[2][4];
  #pragma unroll
  for (int mf = 0; mf < 2; ++mf)
    #pragma unroll
    for (int r = 0; r < 4; ++r) {
      int b = mf * 16 + (l >> 4) * 4 + r;
      creg[mf][r] = a.c_init_bcast ? a.c_init_bcast[col]
                                   : a.c_init_elem[b * HH + col];
    }
  __syncthreads();

  // ---- preload this thread's 16 W fragments into registers (invariant) ----
  bf16x8t wfr[16];
  {
    int wr = w * 16 + lr;
    #pragma unroll
    for (int kf = 0; kf < 16; ++kf) {
      int ka = kf * 32 + kb;
      wfr[kf] = *(const bf16x8t*)((const char*)ldsW +
                ((wr * 1024 + ka * 2) ^ ((wr & 7) << 4)));
    }
  }

  int prow0 = tid >> 7;      // 0 or 1: this thread's first packet row
  int pcp4 = tid & 127;      // fixed column-group (one producer: pcp4>>2)

  // prefetch xw slice for first step
  int s0i = a.backward ? (a.steps - 1) : 0;
  float4 xcur = *(const float4*)(a.xw + ((size_t)s0i * 32 + cblk) * 2048 + tid * 8);
  float4 xnext;

  for (int it = 0; it < a.steps; ++it) {
    int s = a.backward ? (a.steps - 1 - it) : it;
    const uint* hsrc = a.hpack + (size_t)(it & 1) * 4096 * 4;
    uint* hdst = a.hpack + (size_t)((it + 1) & 1) * 4096 * 4;

    // ---- batch-load own packets; batch re-poll rounds until tag == it ----
    u32x4 pv[16];
    #pragma unroll
    for (int j = 0; j < 16; ++j) {
      const uint* ap = hsrc + (size_t)((prow0 + 2 * j) * 128 + pcp4) * 4;
      asm volatile("global_load_dwordx4 %0, %1, off sc0 sc1"
                   : "=&v"(pv[j]) : "v"(ap) : "memory");
    }
    asm volatile("s_waitcnt vmcnt(0)" ::: "memory");
    __builtin_amdgcn_sched_barrier(0);
    {
      int guard = 0;
      while (true) {
        uint bad = 0;
        #pragma unroll
        for (int j = 0; j < 16; ++j) bad |= (pv[j][2] ^ (uint)it);
        if (bad == 0) break;
        if (++guard > (1 << 18)) break;   // fail loud, never hang
        __builtin_amdgcn_s_sleep(1);
        #pragma unroll
        for (int j = 0; j < 16; ++j) {
          const uint* ap = hsrc + (size_t)((prow0 + 2 * j) * 128 + pcp4) * 4;
          asm volatile("global_load_dwordx4 %0, %1, off sc0 sc1"
                       : "=&v"(pv[j]) : "v"(ap) : "memory");
        }
        asm volatile("s_waitcnt vmcnt(0)" ::: "memory");
        __builtin_amdgcn_sched_barrier(0);
      }
    }
    __syncthreads();                      // A: prior iter's LDS readers done

    // ---- stage h into swizzled LDS (8B per packet) + xw ----
    #pragma unroll
    for (int j = 0; j < 16; ++j) {
      int row = prow0 + 2 * j;
      int byte = (row * 1024 + pcp4 * 8) ^ ((row & 7) << 4);
      *(u64t*)((char*)ldsH + byte) = ((u64t)pv[j][1] << 32) | (u64t)pv[j][0];
    }
    *(float4*)&ldsX[tid * 8] = xcur;
    __syncthreads();                      // B: staging visible

    // ---- MFMA: 2 M-tiles x 1 N-tile x 16 K-steps (B from registers) ----
    f32x4 acc0 = (f32x4){0.f, 0.f, 0.f, 0.f};
    f32x4 acc1 = (f32x4){0.f, 0.f, 0.f, 0.f};
    #pragma unroll
    for (int kf = 0; kf < 16; ++kf) {
      int ka = kf * 32 + kb;
      bf16x8t av0 = *(const bf16x8t*)((const char*)ldsH + ((lr * 1024 + ka * 2) ^ ((lr & 7) << 4)));
      bf16x8t av1 = *(const bf16x8t*)((const char*)ldsH + (((16 + lr) * 1024 + ka * 2) ^ (((16 + lr) & 7) << 4)));
      acc0 = __builtin_amdgcn_mfma_f32_16x16x32_bf16(av0, wfr[kf], acc0, 0, 0, 0);
      acc1 = __builtin_amdgcn_mfma_f32_16x16x32_bf16(av1, wfr[kf], acc1, 0, 0, 0);
    }

    // ---- gates: quad-parallel activation, then exchange; pack 4 cols ----
    u64t pk[2][4];
    #pragma unroll
    for (int mf = 0; mf < 2; ++mf) {
      f32x4 ac = mf ? acc1 : acc0;
      #pragma unroll
      for (int r = 0; r < 4; ++r) {
        int b = mf * 16 + (l >> 4) * 4 + r;
        float v = ac[r] + bf2f(ldsX[b * 64 + n]);
        float av = (g == 2) ? ftanh(v) : fsigmoid(v);
        float a1 = __shfl_xor(av, 1);
        float a2 = __shfl_xor(av, 2);
        float a3 = __shfl_xor(av, 3);
        float hnew = 0.f;
        if (g == 0) {
          float iv = av, fv = a1, gv = a2, ov = a3;
          float cnew = fv * creg[mf][r] + iv * gv;
          hnew = ov * ftanh(cnew);
          creg[mf][r] = cnew;
          if (a.h_final && it == a.steps - 1) {
            a.h_final[b * HH + col] = hnew;
            a.c_final[b * HH + col] = cnew;
          }
        }
        uint hu = (uint)f2bf(hnew);
        uint p1 = __shfl_xor(hu, 4);
        uint p2 = __shfl_xor(hu, 8);
        uint p3 = __shfl_xor(p1, 8);
        uint lo = hu | (p1 << 16);
        uint hi = p2 | (p3 << 16);
        pk[mf][r] = ((u64t)hi << 32) | (u64t)lo;
      }
    }

    // ---- packet stores: single dwordx4 each, fire & forget ----
    if ((l & 15) == 0 && it + 1 < a.steps) {
      int cp4w = cblk * 4 + w;
      #pragma unroll
      for (int mf = 0; mf < 2; ++mf)
        #pragma unroll
        for (int r = 0; r < 4; ++r) {
          int b = mf * 16 + (l >> 4) * 4 + r;
          u32x4 pkt;
          pkt[0] = (uint)pk[mf][r];
          pkt[1] = (uint)(pk[mf][r] >> 32);
          pkt[2] = (uint)(it + 1);
          pkt[3] = 0u;
          uint* dp = hdst + (size_t)(b * 128 + cp4w) * 4;
          asm volatile("global_store_dwordx4 %0, %1, off sc0 sc1"
                       :: "v"(dp), "v"(pkt) : "memory");
        }
    }

    // ---- off critical path: out_h stores + next xw prefetch ----
    if ((l & 15) == 0) {
      #pragma unroll
      for (int mf = 0; mf < 2; ++mf)
        #pragma unroll
        for (int r = 0; r < 4; ++r) {
          int b = mf * 16 + (l >> 4) * 4 + r;
          *(u64t*)(a.out_h + (size_t)s * BB * a.out_os + b * a.out_os +
                   a.out_ofs + c0 + w * 4) = pk[mf][r];
        }
    }
    if (it + 1 < a.steps) {
      int sn = a.backward ? (a.steps - 2 - it) : (it + 1);
      const ushort* xp = a.xw + ((size_t)sn * 32 + cblk) * 2048 + tid * 8;
      asm volatile("global_load_dwordx4 %0, %1, off"
                   : "=&v"(xnext) : "v"(xp) : "memory");
    }
    xcur = xnext;
  }
}

// ---------------------------------------------------------------------------
// decoder init: dh packets (tag 0, slot 0) + dc fp32
// ---------------------------------------------------------------------------
__global__ __launch_bounds__(256) void dec_init_kernel(
    const float* __restrict__ hf, const float* __restrict__ hb,
    const float* __restrict__ cf, const float* __restrict__ cb,
    const float* __restrict__ Wh, const float* __restrict__ Wc,
    uint* __restrict__ dh_pack, float* __restrict__ dc)
{
  int b = blockIdx.x;
  __shared__ float hcat[2 * HH], ccat[2 * HH];
  __shared__ ushort dhs[HH];
  int tid = threadIdx.x;
  for (int i = tid; i < HH; i += 256) {
    hcat[i] = hf[b * HH + i]; hcat[HH + i] = hb[b * HH + i];
    ccat[i] = cf[b * HH + i]; ccat[HH + i] = cb[b * HH + i];
  }
  __syncthreads();
  for (int col = tid; col < HH; col += 256) {
    const float4* wh = (const float4*)(Wh + (size_t)col * (2 * HH));
    const float4* wc = (const float4*)(Wc + (size_t)col * (2 * HH));
    float ah = 0.f, acv = 0.f;
    #pragma unroll 4
    for (int k4 = 0; k4 < (2 * HH) / 4; ++k4) {
      float4 h4 = *(const float4*)&hcat[k4 * 4];
      float4 w4 = wh[k4];
      ah += h4.x * w4.x + h4.y * w4.y + h4.z * w4.z + h4.w * w4.w;
      float4 c4 = *(const float4*)&ccat[k4 * 4];
      float4 v4 = wc[k4];
      acv += c4.x * v4.x + c4.y * v4.y + c4.z * v4.z + c4.w * v4.w;
    }
    dhs[col] = f2bf(ah);
    dc[b * HH + col] = acv;
  }
  __syncthreads();
  if (tid < 128) {
    int c = tid * 4;
    uint lo = (uint)dhs[c] | ((uint)dhs[c + 1] << 16);
    uint hi = (uint)dhs[c + 2] | ((uint)dhs[c + 3] << 16);
    u32x4 pkt = {lo, hi, 0u, 0u};
    *(u32x4*)(dh_pack + (size_t)(b * 128 + tid) * 4) = pkt;
  }
}

// ---------------------------------------------------------------------------
__global__ __launch_bounds__(256) void scores_kernel(
    const ushort* __restrict__ keys_bf, const ushort* __restrict__ dhall,
    const int* __restrict__ slen, float* __restrict__ sc)
{
  int b = blockIdx.x & 31, s0 = ((int)blockIdx.x >> 5) * 16;
  __shared__ ushort ldsD[64][520];
  __shared__ ushort ldsK[16][520];
  int tid = threadIdx.x;
  #pragma unroll
  for (int j = 0; j < 16; ++j) {
    int ci = tid + 256 * j;
    int row = ci >> 6, c8 = (ci & 63) * 8;
    *(u16x8*)&ldsD[row][c8] = *(const u16x8*)(dhall + ((size_t)row * BB + b) * HH + c8);
  }
  #pragma unroll
  for (int j = 0; j < 4; ++j) {
    int ci = tid + 256 * j;
    int row = ci >> 6, c8 = (ci & 63) * 8;
    *(u16x8*)&ldsK[row][c8] = *(const u16x8*)(keys_bf + ((size_t)(s0 + row) * BB + b) * HH + c8);
  }
  __syncthreads();

  int sl = tid & 15, tq = tid >> 4;
  float acc[4] = {0.f, 0.f, 0.f, 0.f};
  for (int k8 = 0; k8 < 64; ++k8) {
    float kv[8];
    unpack8(*(const uint4*)&ldsK[sl][k8 * 8], kv);
    #pragma unroll
    for (int j = 0; j < 4; ++j) {
      float dv[8];
      unpack8(*(const uint4*)&ldsD[tq * 4 + j][k8 * 8], dv);
      #pragma unroll
      for (int e = 0; e < 8; ++e) acc[j] += kv[e] * dv[e];
    }
  }
  int s = s0 + sl;
  int len = slen[b];
  #pragma unroll
  for (int j = 0; j < 4; ++j) {
    int t = tq * 4 + j;
    sc[((size_t)t * BB + b) * SS + s] = (s < len) ? acc[j] : -1e18f;
  }
}

__global__ __launch_bounds__(64) void softmax_kernel(
    const float* __restrict__ sc, ushort* __restrict__ wbf)
{
  int row = blockIdx.x;
  int tid = threadIdx.x;
  float v[7];
  float m = -3e38f;
  #pragma unroll
  for (int j = 0; j < 7; ++j) {
    int s = tid + 64 * j;
    v[j] = (s < SS) ? sc[(size_t)row * SS + s] : -3e38f;
    m = fmaxf(m, v[j]);
  }
  #pragma unroll
  for (int o = 32; o; o >>= 1) m = fmaxf(m, __shfl_xor(m, o));
  float ssum = 0.f;
  float p[7];
  #pragma unroll
  for (int j = 0; j < 7; ++j) {
    int s = tid + 64 * j;
    p[j] = (s < SS) ? __expf(v[j] - m) : 0.f;
    ssum += p[j];
  }
  #pragma unroll
  for (int o = 32; o; o >>= 1) ssum += __shfl_xor(ssum, o);
  float inv = 1.f / ssum;
  #pragma unroll
  for (int j = 0; j < 7; ++j) {
    int s = tid + 64 * j;
    if (s < 416) wbf[(size_t)row * 416 + s] = (s < SS) ? f2bf(p[j] * inv) : (ushort)0;
  }
}

// ---------------------------------------------------------------------------
__global__ __launch_bounds__(256) void context_kernel(
    const ushort* __restrict__ wbf, const ushort* __restrict__ enc,
    const ushort* __restrict__ dhall, ushort* __restrict__ catb)
{
  int b = blockIdx.x, ch = blockIdx.y;
  int tid = threadIdx.x;
  if (ch >= 16) {
    int c0 = (ch - 16) * 64;
    #pragma unroll
    for (int j = 0; j < 2; ++j) {
      int ci = tid + 256 * j;
      int t = ci >> 3, u = ci & 7;
      *(u16x8*)(catb + ((size_t)t * BB + b) * 1536 + 1024 + c0 + u * 8) =
          *(const u16x8*)(dhall + ((size_t)t * BB + b) * HH + c0 + u * 8);
    }
    return;
  }
  int d0 = ch * 64;
  __shared__ ushort ldsWt[64][424];
  for (int ci = tid; ci < 64 * 52; ci += 256) {
    int t = ci / 52, u = ci % 52;
    *(u16x8*)&ldsWt[t][u * 8] = *(const u16x8*)(wbf + (size_t)(t * BB + b) * 416 + u * 8);
  }
  __syncthreads();

  int d = d0 + (tid & 63), tq = tid >> 6;
  float acc16[16];
  #pragma unroll
  for (int i = 0; i < 16; ++i) acc16[i] = 0.f;

  for (int s8 = 0; s8 < 50; ++s8) {
    float ev[8];
    #pragma unroll
    for (int e = 0; e < 8; ++e)
      ev[e] = bf2f(enc[((size_t)(s8 * 8 + e) * BB + b) * 1024 + d]);
    #pragma unroll
    for (int i = 0; i < 16; ++i) {
      float wv[8];
      unpack8(*(const uint4*)&ldsWt[tq * 16 + i][s8 * 8], wv);
      #pragma unroll
      for (int e = 0; e < 8; ++e) acc16[i] += wv[e] * ev[e];
    }
  }
  #pragma unroll
  for (int i = 0; i < 16; ++i) {
    int t = tq * 16 + i;
    catb[((size_t)t * BB + b) * 1536 + d] = f2bf(acc16[i]);
  }
}

// ---------------------------------------------------------------------------
__global__ __launch_bounds__(1024) void logsoftmax_kernel(float* __restrict__ out)
{
  int r = blockIdx.x;
  __shared__ float row[VV];
  __shared__ float red[16];
  int tid = threadIdx.x;
  float4* p = (float4*)(out + (size_t)r * VV);
  float4* rp = (float4*)row;
  float m = -3e38f;
  #pragma unroll
  for (int j = 0; j < 8; ++j) {
    int i = tid + 1024 * j;
    if (i < VV / 4) {
      float4 v = p[i];
      rp[i] = v;
      m = fmaxf(m, fmaxf(fmaxf(v.x, v.y), fmaxf(v.z, v.w)));
    }
  }
  #pragma unroll
  for (int o = 32; o; o >>= 1) m = fmaxf(m, __shfl_xor(m, o));
  if ((tid & 63) == 0) red[tid >> 6] = m;
  __syncthreads();
  float mm = red[0];
  #pragma unroll
  for (int i = 1; i < 16; ++i) mm = fmaxf(mm, red[i]);
  __syncthreads();
  float ssum = 0.f;
  #pragma unroll
  for (int j = 0; j < 8; ++j) {
    int i = tid + 1024 * j;
    if (i < VV / 4) {
      float4 v = rp[i];
      ssum += __expf(v.x - mm) + __expf(v.y - mm) + __expf(v.z - mm) + __expf(v.w - mm);
    }
  }
  #pragma unroll
  for (int o = 32; o; o >>= 1) ssum += __shfl_xor(ssum, o);
  if ((tid & 63) == 0) red[tid >> 6] = ssum;
  __syncthreads();
  float st = red[0];
  #pragma unroll
  for (int i = 1; i < 16; ++i) st += red[i];
  st = mm + logf(st);
  #pragma unroll
  for (int j = 0; j < 8; ++j) {
    int i = tid + 1024 * j;
    if (i < VV / 4) {
      float4 v = rp[i];
      v.x -= st; v.y -= st; v.z -= st; v.w -= st;
      p[i] = v;
    }
  }
}

// ---------------------------------------------------------------------------
extern "C" void kernel_launch(void* const* d_in, const int* in_sizes, int n_in,
                              void* d_out, int out_size, void* d_ws, size_t ws_size,
                              hipStream_t stream)
{
  (void)in_sizes; (void)n_in; (void)out_size; (void)ws_size;
  const int*   src  = (const int*)d_in[0];
  const int*   slen = (const int*)d_in[1];
  const int*   tgt  = (const int*)d_in[2];
  const float* emb  = (const float*)d_in[3];
  const float* eWif = (const float*)d_in[4];
  const float* eWhf = (const float*)d_in[5];
  const float* ebif = (const float*)d_in[6];
  const float* ebhf = (const float*)d_in[7];
  const float* eWib = (const float*)d_in[8];
  const float* eWhb = (const float*)d_in[9];
  const float* ebib = (const float*)d_in[10];
  const float* ebhb = (const float*)d_in[11];
  const float* einh = (const float*)d_in[12];
  const float* einc = (const float*)d_in[13];
  const float* dhW  = (const float*)d_in[14];
  const float* dcW  = (const float*)d_in[15];
  const float* cWi  = (const float*)d_in[16];
  const float* cWh  = (const float*)d_in[17];
  const float* cbi  = (const float*)d_in[18];
  const float* cbh  = (const float*)d_in[19];
  const float* aW   = (const float*)d_in[20];
  const float* abv  = (const float*)d_in[21];
  const float* ccW  = (const float*)d_in[22];
  const float* ccbv = (const float*)d_in[23];
  const float* oW   = (const float*)d_in[24];
  const float* obv  = (const float*)d_in[25];
  float* out = (float*)d_out;
  float* ws  = (float*)d_ws;

  // ---------- workspace layout (float units) ----------
  size_t off = 0;
  ushort* enc_bf  = (ushort*)(ws + off); off += (size_t)SS * BB * 1024 / 2;
  ushort* keys_bf = (ushort*)(ws + off); off += (size_t)SS * BB * HH / 2;
  ushort* dhall_bf= (ushort*)(ws + off); off += (size_t)TT * BB * HH / 2;
  ushort* catb_bf = (ushort*)(ws + off); off += (size_t)TT * BB * 1536 / 2;
  ushort* ccv_bf  = (ushort*)(ws + off); off += (size_t)TT * BB * HH / 2;
  float*  scbuf   = ws + off;            off += (size_t)TT * BB * SS;
  ushort* w_bf    = (ushort*)(ws + off); off += (size_t)TT * BB * 416 / 2;
  ushort* xe_bf   = (ushort*)(ws + off); off += (size_t)SS * BB * EE / 2;
  ushort* xd_bf   = (ushort*)(ws + off); off += (size_t)TT * BB * EE / 2;
  ushort* xWf_bf  = (ushort*)(ws + off); off += (size_t)SS * BB * 2048 / 2;
  ushort* xWb_bf  = (ushort*)(ws + off); off += (size_t)SS * BB * 2048 / 2;
  ushort* xWd_bf  = (ushort*)(ws + off); off += (size_t)TT * BB * 2048 / 2;
  ushort* oW_bf   = (ushort*)(ws + off); off += (size_t)VV * HH / 2;
  ushort* aW_bf   = (ushort*)(ws + off); off += (size_t)HH * 1024 / 2;
  ushort* ccW_bf  = (ushort*)(ws + off); off += (size_t)HH * 1536 / 2;
  ushort* eWif_bf = (ushort*)(ws + off); off += (size_t)2048 * EE / 2;
  ushort* eWib_bf = (ushort*)(ws + off); off += (size_t)2048 * EE / 2;
  ushort* cWi_bf  = (ushort*)(ws + off); off += (size_t)2048 * EE / 2;
  // packet buffers: [2 slots][32 b][128 cp4] x 16B each; contiguous for memset
  uint* hge_pack = (uint*)(ws + off); off += (size_t)2 * 4096 * 4;
  uint* hgb_pack = (uint*)(ws + off); off += (size_t)2 * 4096 * 4;
  uint* hdec_pack= (uint*)(ws + off); off += (size_t)2 * 4096 * 4;
  float* bias3 = ws + off; off += 3 * 2048;
  float* hf_f  = ws + off; off += BB * HH;
  float* hb_f  = ws + off; off += BB * HH;
  float* cf_f  = ws + off; off += BB * HH;
  float* cb_f  = ws + off; off += BB * HH;
  float* dcb   = ws + off; off += BB * HH;

  // 0. zero packet buffers (tags) -- protects the first (unpoisoned) call
  hipMemsetAsync(hge_pack, 0, (size_t)3 * 2 * 4096 * 16, stream);

  // 1. initial-h packets for encoder
  init_all_kernel<<<64, 256, 0, stream>>>(einh, hge_pack, hgb_pack);

  // 2. weight conversions (oW folded into encoder kernel below)
  f2bf_kernel<<<512, 256, 0, stream>>>(aW, aW_bf, (long)HH * 1024);
  f2bf_kernel<<<512, 256, 0, stream>>>(ccW, ccW_bf, (long)HH * 1536);
  f2bf_kernel<<<512, 256, 0, stream>>>(eWif, eWif_bf, (long)2048 * EE);
  f2bf_kernel<<<512, 256, 0, stream>>>(eWib, eWib_bf, (long)2048 * EE);
  f2bf_kernel<<<512, 256, 0, stream>>>(cWi, cWi_bf, (long)2048 * EE);
  bias3_kernel<<<24, 256, 0, stream>>>(ebif, ebhf, ebib, ebhb, cbi, cbh, bias3);

  // 3. x gathers + xW GEMMs (bias folded, xw-layout bf16 out)
  gather_x_kernel<<<SS * BB, 64, 0, stream>>>(emb, src, SS, xe_bf);
  gather_x_kernel<<<TT * BB, 64, 0, stream>>>(emb, tgt, TT, xd_bf);
  gemm_mfma_kernel<<<dim3(2048 / 128, (SS * BB) / 128), 256, 0, stream>>>(
      xe_bf, eWif_bf, bias3, xWf_bf, SS * BB, 2048, EE, 8);
  gemm_mfma_kernel<<<dim3(2048 / 128, (SS * BB) / 128), 256, 0, stream>>>(
      xe_bf, eWib_bf, bias3 + 2048, xWb_bf, SS * BB, 2048, EE, 8);
  gemm_mfma_kernel<<<dim3(2048 / 128, (TT * BB) / 128), 256, 0, stream>>>(
      xd_bf, cWi_bf, bias3 + 4096, xWd_bf, TT * BB, 2048, EE, 8);

  // 4. persistent bi-encoder (400 steps) + 192 converter blocks for oW
  {
    PersistArgs af, ab;
    af.W_hh = eWhf; af.xw = xWf_bf; af.hpack = hge_pack;
    af.c_init_elem = nullptr; af.c_init_bcast = einc;
    af.out_h = enc_bf; af.out_os = 1024; af.out_ofs = 0;
    af.steps = SS; af.backward = 0;
    af.h_final = hf_f; af.c_final = cf_f;
    ab = af;
    ab.W_hh = eWhb; ab.xw = xWb_bf; ab.hpack = hgb_pack;
    ab.c_init_bcast = einc + HH;
    ab.out_ofs = HH; ab.backward = 1;
    ab.h_final = hb_f; ab.c_final = cb_f;
    lstm_persist_kernel<<<256, 256, 0, stream>>>(af, ab, 32,
                                                 oW, oW_bf, (long)VV * HH);
  }

  // 5. decoder init + persistent decoder (64 steps)
  dec_init_kernel<<<BB, 256, 0, stream>>>(hf_f, hb_f, cf_f, cb_f, dhW, dcW,
                                          hdec_pack, dcb);
  {
    PersistArgs ad;
    ad.W_hh = cWh; ad.xw = xWd_bf; ad.hpack = hdec_pack;
    ad.c_init_elem = dcb; ad.c_init_bcast = nullptr;
    ad.out_h = dhall_bf; ad.out_os = HH; ad.out_ofs = 0;
    ad.steps = TT; ad.backward = 0;
    ad.h_final = nullptr; ad.c_final = nullptr;
    lstm_persist_kernel<<<32, 256, 0, stream>>>(ad, ad, 32,
                                                nullptr, nullptr, 0);
  }

  // 6. attention keys GEMM (bf16 out)
  gemm_mfma_kernel<<<dim3(HH / 128, (SS * BB) / 128), 256, 0, stream>>>(
      enc_bf, aW_bf, abv, keys_bf, SS * BB, HH, 1024, 4);

  // 7. attention: scores -> softmax -> context/copy
  scores_kernel<<<32 * 25, 256, 0, stream>>>(keys_bf, dhall_bf, slen, scbuf);
  softmax_kernel<<<TT * BB, 64, 0, stream>>>(scbuf, w_bf);
  context_kernel<<<dim3(BB, 24), 256, 0, stream>>>(w_bf, enc_bf, dhall_bf, catb_bf);

  // 8. concat + output GEMMs
  gemm_mfma_kernel<<<dim3(HH / 128, (TT * BB) / 128), 256, 0, stream>>>(
      catb_bf, ccW_bf, ccbv, ccv_bf, TT * BB, HH, 1536, 1 | 4);
  gemm_mfma_kernel<<<dim3(VV / 128, (TT * BB) / 128), 256, 0, stream>>>(
      ccv_bf, oW_bf, obv, out, TT * BB, VV, HH, 2);

  // 9. fused log-softmax
  logsoftmax_kernel<<<TT * BB, 1024, 0, stream>>>(out);
}